// Round 2
// baseline (313.346 us; speedup 1.0000x reference)
//
#include <hip/hip_runtime.h>
#include <hip/hip_bf16.h>
#include <cstdint>

// Problem constants (fixed by the reference).
#define CDIM   256      // channels == code dim
#define NCODES 256
#define HWB    32768    // H*W = 128*256
#define BATCH  4
#define BN     64       // pixels per block tile

typedef __bf16 bf16x8 __attribute__((ext_vector_type(8)));
typedef float  f32x4  __attribute__((ext_vector_type(4)));

// ---------------------------------------------------------------------------
// prep: fused norms + M-matrix build.
// Block i (256 blocks, 256 threads) computes row i of
//   M[i][j] = sum_n cb[n][i] * cb[n][j] / ||cb[n]||^2   (stored bf16).
// Phase 1: each wave computes 64 norms cooperatively (coalesced loads +
// shuffle reduce), storing g[n] = cb[n][i]/norm into LDS.
// Phase 2: per-thread j: acc += g[n] * cb[n][j]  (g = LDS broadcast,
// cb coalesced, L2-hot).
// ---------------------------------------------------------------------------
__global__ __launch_bounds__(256) void prep_kernel(
    const float* __restrict__ cb, __bf16* __restrict__ Mb) {
    __shared__ float g[NCODES];
    const int i    = blockIdx.x;
    const int tid  = threadIdx.x;
    const int lane = tid & 63;
    const int w    = tid >> 6;

#pragma unroll 4
    for (int r = 0; r < 64; ++r) {
        const int n = w * 64 + r;
        const float* row = cb + n * CDIM;
        float v0 = row[lane], v1 = row[lane + 64],
              v2 = row[lane + 128], v3 = row[lane + 192];
        float s = v0 * v0 + v1 * v1 + v2 * v2 + v3 * v3;
#pragma unroll
        for (int off = 32; off > 0; off >>= 1) s += __shfl_down(s, off, 64);
        if (lane == 0) g[n] = cb[n * CDIM + i] / s;
    }
    __syncthreads();

    float acc = 0.f;
#pragma unroll 8
    for (int n = 0; n < NCODES; ++n)
        acc += g[n] * cb[n * CDIM + tid];
    Mb[i * CDIM + tid] = (__bf16)acc;
}

// ---------------------------------------------------------------------------
// recon: out[b,c,p] = sum_k M[c][k] * feat[b,k,p].
// NO LDS, NO BARRIERS — pure register streaming.
//  - A-frags (M, bf16, L2-hot): dwordx4 loads, kc*64B offset immediates.
//  - B-frags: per-lane dword loads of feat[k][p0+nt*16+l16]; for fixed (k),
//    the 16 l16-lanes are consecutive -> 4x64B coalesced segments per instr.
//    4x wave replication within the block is L1-served (8KB/chunk).
//  - 2-stage software pipeline (fv/af double-buffered in registers) keeps
//    ~8KB/wave of global loads in flight with zero s_barrier.
// Block = 256 thr (4 waves), tile 256(c) x 64(p), K-loop 8 chunks of 32.
// VGPR ~ 64 acc + 64 fv + 16 af + 16 ptrs + misc ~ 190 -> 2 waves/SIMD.
// ---------------------------------------------------------------------------
__global__ __launch_bounds__(256, 2) void recon_kernel(
    const float* __restrict__ feat, const __bf16* __restrict__ Mb,
    float* __restrict__ out) {
    const int tid  = threadIdx.x;
    const int lane = tid & 63;
    const int w    = tid >> 6;       // wave 0..3 -> c-rows [w*64, w*64+64)
    const int quad = lane >> 4;      // 0..3
    const int l16  = lane & 15;

    const int b  = blockIdx.y;
    const int p0 = blockIdx.x * BN;

    const float* fbase = feat + ((size_t)b * CDIM) * HWB + p0 + l16;
    float*       obase = out  + ((size_t)b * CDIM) * HWB + p0;

    // 8 feature row pointers: k = quad*8 + j (advanced by 32 rows per kc)
    const float* fptr[8];
#pragma unroll
    for (int j = 0; j < 8; ++j) fptr[j] = fbase + (size_t)(quad * 8 + j) * HWB;

    // 4 M row pointers: row = w*64 + mt*16 + l16, col base quad*8
    const __bf16* aptr[4];
#pragma unroll
    for (int mt = 0; mt < 4; ++mt)
        aptr[mt] = Mb + ((w * 64 + mt * 16 + l16) * CDIM + quad * 8);

    f32x4 acc[4][4];
#pragma unroll
    for (int mt = 0; mt < 4; ++mt)
#pragma unroll
        for (int nt = 0; nt < 4; ++nt)
            acc[mt][nt] = (f32x4){0.f, 0.f, 0.f, 0.f};

    float  fv[2][4][8];
    bf16x8 af[2][4];

    // ---- prologue: stage kc=0 ----
#pragma unroll
    for (int mt = 0; mt < 4; ++mt) af[0][mt] = *(const bf16x8*)(aptr[mt]);
#pragma unroll
    for (int nt = 0; nt < 4; ++nt)
#pragma unroll
        for (int j = 0; j < 8; ++j)
            fv[0][nt][j] = fptr[j][nt * 16];
#pragma unroll
    for (int j = 0; j < 8; ++j) fptr[j] += (size_t)32 * HWB;

#pragma unroll
    for (int kc = 0; kc < 8; ++kc) {
        const int cur = kc & 1, nxt = cur ^ 1;

        // ---- prefetch kc+1 while kc computes ----
        if (kc < 7) {
#pragma unroll
            for (int mt = 0; mt < 4; ++mt)
                af[nxt][mt] = *(const bf16x8*)(aptr[mt] + (kc + 1) * 32);
#pragma unroll
            for (int nt = 0; nt < 4; ++nt)
#pragma unroll
                for (int j = 0; j < 8; ++j)
                    fv[nxt][nt][j] = fptr[j][nt * 16];
#pragma unroll
            for (int j = 0; j < 8; ++j) fptr[j] += (size_t)32 * HWB;
        }

        // ---- convert + MFMA for kc ----
        bf16x8 bfr[4];
#pragma unroll
        for (int nt = 0; nt < 4; ++nt) {
            bf16x8 t;
#pragma unroll
            for (int j = 0; j < 8; ++j) t[j] = (__bf16)fv[cur][nt][j];
            bfr[nt] = t;
        }
#pragma unroll
        for (int mt = 0; mt < 4; ++mt)
#pragma unroll
            for (int nt = 0; nt < 4; ++nt)
                acc[mt][nt] = __builtin_amdgcn_mfma_f32_16x16x32_bf16(
                    af[cur][mt], bfr[nt], acc[mt][nt], 0, 0, 0);
    }

    // ---- epilogue: D[row=quad*4+r][col=l16] per 16x16 tile ----
#pragma unroll
    for (int mt = 0; mt < 4; ++mt) {
#pragma unroll
        for (int r = 0; r < 4; ++r) {
            const int c = w * 64 + mt * 16 + quad * 4 + r;
            float* orow = obase + (size_t)c * HWB + l16;
#pragma unroll
            for (int nt = 0; nt < 4; ++nt)
                orow[nt * 16] = acc[mt][nt][r];
        }
    }
}

// ---------------------------------------------------------------------------
extern "C" void kernel_launch(void* const* d_in, const int* in_sizes, int n_in,
                              void* d_out, int out_size, void* d_ws, size_t ws_size,
                              hipStream_t stream) {
    const float* feat = (const float*)d_in[0];   // [4,256,128,256] fp32
    const float* cb   = (const float*)d_in[1];   // [256,256] fp32
    float* out = (float*)d_out;

    __bf16* Mb = (__bf16*)d_ws;                  // 128 KB bf16 M matrix

    prep_kernel<<<NCODES, 256, 0, stream>>>(cb, Mb);

    dim3 grid(HWB / BN, BATCH);   // 512 x 4 blocks
    recon_kernel<<<grid, 256, 0, stream>>>(feat, Mb, out);
}

// Round 3
// 295.155 us; speedup vs baseline: 1.0616x; 1.0616x over previous
//
#include <hip/hip_runtime.h>
#include <hip/hip_bf16.h>
#include <cstdint>

// Problem constants (fixed by the reference).
#define CDIM   256      // channels == code dim
#define NCODES 256
#define HWB    32768    // H*W = 128*256
#define BATCH  4
#define BM     128      // c-rows per block tile
#define BN     64       // pixels per block tile
#define BK     32       // K-chunk
#define NKC    8        // 256 / BK

typedef __bf16 bf16x8 __attribute__((ext_vector_type(8)));
typedef float  f32x4  __attribute__((ext_vector_type(4)));

// 16B/lane async global->LDS (dest = uniform base + lane*16, contiguous).
#define GLDS(g, l)                                                         \
    __builtin_amdgcn_global_load_lds(                                      \
        (const __attribute__((address_space(1))) void*)(g),                \
        (__attribute__((address_space(3))) void*)(l), 16, 0, 0)

// ---------------------------------------------------------------------------
// prep: fused norms + M-matrix build (unchanged from r2 — passed, ~fast).
// Block i computes row i of M[i][j] = sum_n cb[n][i]*cb[n][j]/||cb[n]||^2.
// ---------------------------------------------------------------------------
__global__ __launch_bounds__(256) void prep_kernel(
    const float* __restrict__ cb, __bf16* __restrict__ Mb) {
    __shared__ float g[NCODES];
    const int i    = blockIdx.x;
    const int tid  = threadIdx.x;
    const int lane = tid & 63;
    const int w    = tid >> 6;

#pragma unroll 4
    for (int r = 0; r < 64; ++r) {
        const int n = w * 64 + r;
        const float* row = cb + n * CDIM;
        float v0 = row[lane], v1 = row[lane + 64],
              v2 = row[lane + 128], v3 = row[lane + 192];
        float s = v0 * v0 + v1 * v1 + v2 * v2 + v3 * v3;
#pragma unroll
        for (int off = 32; off > 0; off >>= 1) s += __shfl_down(s, off, 64);
        if (lane == 0) g[n] = cb[n * CDIM + i] / s;
    }
    __syncthreads();

    float acc = 0.f;
#pragma unroll 8
    for (int n = 0; n < NCODES; ++n)
        acc += g[n] * cb[n * CDIM + tid];
    Mb[i * CDIM + tid] = (__bf16)acc;
}

// ---------------------------------------------------------------------------
// recon: out[b,c,p] = sum_k M[c][k] * feat[b,k,p].
// SINGLE-WAVE blocks (64 thr): no __syncthreads anywhere.
// 2-stage LDS pipeline fed exclusively by global_load_lds (16B granules),
// gated by hand-placed s_waitcnt vmcnt(16): stage i+1's 16 KB stays in
// flight while stage i computes. 32 KB LDS/block -> 5 blocks/CU -> ~80 KB
// of HBM loads in flight per CU (BDP ~9 KB) — latency fully covered.
//  - A stage: M rows [c0, c0+128) x 32k, bf16, LDS [r][k] row-major (64B rows).
//  - B stage: feat 32k x 64p, fp32, LDS [k][p] row-major (256B rows);
//    converted to bf16 at fragment-read time.
// Per kc: 8x ds_read_b128 (A frags), 32x ds_read_b32 + cvt (B frags),
// 32 MFMA (8 mt x 4 nt). acc = 8x4 f32x4 = 128 regs.
// ---------------------------------------------------------------------------
__global__ __launch_bounds__(64, 2) void recon_kernel(
    const float* __restrict__ feat, const __bf16* __restrict__ Mb,
    float* __restrict__ out) {
    __shared__ __align__(16) __bf16 Albuf[2][BM * BK];   // 2 x 8 KB
    __shared__ __align__(16) float  Blbuf[2][BK * BN];   // 2 x 8 KB

    const int lane = threadIdx.x;
    const int quad = lane >> 4;      // 0..3
    const int l16  = lane & 15;

    const int p0 = blockIdx.x * BN;
    const int c0 = blockIdx.y * BM;
    const int b  = blockIdx.z;

    const float* fbase = feat + ((size_t)b * CDIM) * HWB + p0;
    float*       obase = out  + ((size_t)b * CDIM) * HWB + p0;

    // Per-lane source addresses for the staging granules.
    //  A instr h (h=0..7): lane -> M row c0+16h+lane/4, k-bytes (lane%4)*16.
    //  B instr g (g=0..7): lane -> feat row 4g+lane/16, p-bytes (lane%16)*16.
    const __bf16* asrc = Mb + (c0 + (lane >> 2)) * CDIM + (lane & 3) * 8;
    const float*  bsrc = fbase + (size_t)(lane >> 4) * HWB + (lane & 15) * 4;

    auto issue = [&](int s) {
        const int buf = s & 1;
#pragma unroll
        for (int h = 0; h < 8; ++h)
            GLDS(asrc + (h * 16) * CDIM + s * BK, &Albuf[buf][h * 512]);
#pragma unroll
        for (int g = 0; g < 8; ++g)
            GLDS(bsrc + (size_t)(s * BK + g * 4) * HWB, &Blbuf[buf][g * 256]);
    };

    f32x4 acc[8][4];
#pragma unroll
    for (int mt = 0; mt < 8; ++mt)
#pragma unroll
        for (int nt = 0; nt < 4; ++nt)
            acc[mt][nt] = (f32x4){0.f, 0.f, 0.f, 0.f};

    issue(0);
    issue(1);

#pragma unroll
    for (int s = 0; s < NKC; ++s) {
        const int buf = s & 1;
        // Stage s ready when only stage s+1's 16 loads remain outstanding.
        if (s < NKC - 1) asm volatile("s_waitcnt vmcnt(16)" ::: "memory");
        else             asm volatile("s_waitcnt vmcnt(0)"  ::: "memory");

        bf16x8 af[8];
#pragma unroll
        for (int mt = 0; mt < 8; ++mt)
            af[mt] = *(const bf16x8*)&Albuf[buf][(mt * 16 + l16) * BK + quad * 8];

        bf16x8 bfr[4];
#pragma unroll
        for (int nt = 0; nt < 4; ++nt) {
            bf16x8 t;
#pragma unroll
            for (int j = 0; j < 8; ++j)
                t[j] = (__bf16)Blbuf[buf][(quad * 8 + j) * BN + nt * 16 + l16];
            bfr[nt] = t;
        }

        // LDS reads drained before stage s+2 overwrites this buffer.
        asm volatile("s_waitcnt lgkmcnt(0)" ::: "memory");
        if (s + 2 < NKC) issue(s + 2);

#pragma unroll
        for (int mt = 0; mt < 8; ++mt)
#pragma unroll
            for (int nt = 0; nt < 4; ++nt)
                acc[mt][nt] = __builtin_amdgcn_mfma_f32_16x16x32_bf16(
                    af[mt], bfr[nt], acc[mt][nt], 0, 0, 0);
    }

    // Epilogue: D[row=quad*4+r][col=l16] per 16x16 tile.
#pragma unroll
    for (int mt = 0; mt < 8; ++mt) {
#pragma unroll
        for (int r = 0; r < 4; ++r) {
            const int c = c0 + mt * 16 + quad * 4 + r;
            float* orow = obase + (size_t)c * HWB + l16;
#pragma unroll
            for (int nt = 0; nt < 4; ++nt)
                orow[nt * 16] = acc[mt][nt][r];
        }
    }
}

// ---------------------------------------------------------------------------
extern "C" void kernel_launch(void* const* d_in, const int* in_sizes, int n_in,
                              void* d_out, int out_size, void* d_ws, size_t ws_size,
                              hipStream_t stream) {
    const float* feat = (const float*)d_in[0];   // [4,256,128,256] fp32
    const float* cb   = (const float*)d_in[1];   // [256,256] fp32
    float* out = (float*)d_out;

    __bf16* Mb = (__bf16*)d_ws;                  // 128 KB bf16 M matrix

    prep_kernel<<<NCODES, 256, 0, stream>>>(cb, Mb);

    dim3 grid(HWB / BN, CDIM / BM, BATCH);       // 512 x 2 x 4 single-wave blocks
    recon_kernel<<<grid, 64, 0, stream>>>(feat, Mb, out);
}

// Round 4
// 292.427 us; speedup vs baseline: 1.0715x; 1.0093x over previous
//
#include <hip/hip_runtime.h>
#include <hip/hip_bf16.h>
#include <cstdint>

// Problem constants (fixed by the reference).
#define CDIM   256      // channels == code dim
#define NCODES 256
#define HWB    32768    // H*W = 128*256
#define BATCH  4
#define BN     64       // pixels per block tile
#define BK     32       // K-chunk
#define NKC    8        // 256 / BK
#define BPAD   65       // B LDS row stride in floats (bank-conflict-free)

typedef __bf16 bf16x8 __attribute__((ext_vector_type(8)));
typedef float  f32x4  __attribute__((ext_vector_type(4)));

// Async global->LDS. Dest is wave-uniform base + lane*size.
#define GLDS16(g, l)                                                       \
    __builtin_amdgcn_global_load_lds(                                      \
        (const __attribute__((address_space(1))) void*)(g),                \
        (__attribute__((address_space(3))) void*)(l), 16, 0, 0)
#define GLDS4(g, l)                                                        \
    __builtin_amdgcn_global_load_lds(                                      \
        (const __attribute__((address_space(1))) void*)(g),                \
        (__attribute__((address_space(3))) void*)(l), 4, 0, 0)

// ---------------------------------------------------------------------------
// prep: fused norms + M-matrix build (unchanged — correct, cheap).
// Block i computes row i of M[i][j] = sum_n cb[n][i]*cb[n][j]/||cb[n]||^2.
// ---------------------------------------------------------------------------
__global__ __launch_bounds__(256) void prep_kernel(
    const float* __restrict__ cb, __bf16* __restrict__ Mb) {
    __shared__ float g[NCODES];
    const int i    = blockIdx.x;
    const int tid  = threadIdx.x;
    const int lane = tid & 63;
    const int w    = tid >> 6;

#pragma unroll 4
    for (int r = 0; r < 64; ++r) {
        const int n = w * 64 + r;
        const float* row = cb + n * CDIM;
        float v0 = row[lane], v1 = row[lane + 64],
              v2 = row[lane + 128], v3 = row[lane + 192];
        float s = v0 * v0 + v1 * v1 + v2 * v2 + v3 * v3;
#pragma unroll
        for (int off = 32; off > 0; off >>= 1) s += __shfl_down(s, off, 64);
        if (lane == 0) g[n] = cb[n * CDIM + i] / s;
    }
    __syncthreads();

    float acc = 0.f;
#pragma unroll 8
    for (int n = 0; n < NCODES; ++n)
        acc += g[n] * cb[n * CDIM + tid];
    Mb[i * CDIM + tid] = (__bf16)acc;
}

// ---------------------------------------------------------------------------
// recon: out[b,c,p] = sum_k M[c][k] * feat[b,k,p].
// 256-thr blocks (occupancy) + raw s_barrier + fine-grained vmcnt (no drain):
//   - All staging via global_load_lds (compiler cannot sink it), 2-stage
//     double buffer, 12 VMEM instr per wave per stage.
//   - Before reading stage s: s_waitcnt vmcnt(12) — waits only for MY stage-s
//     loads; stage s+1's 12 stay in flight. Then s_barrier: since every wave
//     did the same, stage s is collectively complete in LDS. NO vmcnt(0)
//     until the final stage.
//   - After frag reads: lgkmcnt(0) + s_barrier, then issue stage s+2 into the
//     buffer everyone just finished reading.
// Tile 256(c) x 64(p): feature HBM-read exactly once. 3 blocks/CU (49.4 KB
// LDS) -> ~24 KB/stage x 3 in flight per CU >> 9 KB BDP.
// B LDS rows padded to 65 floats: frag-read bank = 8*quad + j + 16*nt + l16
// (row stride 65 ≡ 1 mod 32) -> every bank hit by exactly 2 lanes = free.
// ---------------------------------------------------------------------------
__global__ __launch_bounds__(256, 3) void recon_kernel(
    const float* __restrict__ feat, const __bf16* __restrict__ Mb,
    float* __restrict__ out) {
    __shared__ __align__(16) __bf16 Albuf[2][CDIM * BK];   // 2 x 16 KB
    __shared__ __align__(16) float  Blbuf[2][BK * BPAD];   // 2 x 8.32 KB

    const int tid  = threadIdx.x;
    const int lane = tid & 63;
    const int w    = tid >> 6;       // wave 0..3 -> c-rows [w*64, w*64+64)
    const int quad = lane >> 4;      // 0..3
    const int l16  = lane & 15;

    const int p0 = blockIdx.x * BN;
    const int b  = blockIdx.y;

    const float* fbase = feat + ((size_t)b * CDIM) * HWB + p0;
    float*       obase = out  + ((size_t)b * CDIM) * HWB + p0;

    // A: wave w issues 4 instrs (h=w*4+i), each staging 16 c-rows x 16B.
    //    lane -> c = h*16 + lane/4, k-granule = lane%4 (8 bf16 each).
    // B: wave w issues 8 instrs (r=w*8+i), each staging one k-row of 64 px
    //    (4B/lane) into a 65-float padded LDS row.
    const int a_c  = (lane >> 2);        // + h*16
    const int a_kq = (lane & 3) * 8;

    auto issue = [&](int s) {
        const int buf = s & 1;
#pragma unroll
        for (int i = 0; i < 4; ++i) {
            const int h = w * 4 + i;
            const __bf16* src = Mb + (h * 16 + a_c) * CDIM + s * BK + a_kq;
            GLDS16(src, &Albuf[buf][h * 512]);
        }
#pragma unroll
        for (int i = 0; i < 8; ++i) {
            const int r = w * 8 + i;
            const float* src = fbase + (size_t)(s * BK + r) * HWB + lane;
            GLDS4(src, &Blbuf[buf][r * BPAD]);
        }
    };

    f32x4 acc[4][4];
#pragma unroll
    for (int mt = 0; mt < 4; ++mt)
#pragma unroll
        for (int nt = 0; nt < 4; ++nt)
            acc[mt][nt] = (f32x4){0.f, 0.f, 0.f, 0.f};

    issue(0);
    issue(1);

#pragma unroll
    for (int s = 0; s < NKC; ++s) {
        const int buf = s & 1;
        // My stage-s loads done; stage s+1's 12 remain in flight.
        if (s < NKC - 1) asm volatile("s_waitcnt vmcnt(12)" ::: "memory");
        else             asm volatile("s_waitcnt vmcnt(0)"  ::: "memory");
        asm volatile("s_barrier" ::: "memory");   // everyone's stage-s landed

        bf16x8 af[4];
#pragma unroll
        for (int mt = 0; mt < 4; ++mt)
            af[mt] = *(const bf16x8*)
                &Albuf[buf][(w * 64 + mt * 16 + l16) * BK + quad * 8];

        bf16x8 bfr[4];
#pragma unroll
        for (int nt = 0; nt < 4; ++nt) {
            bf16x8 t;
#pragma unroll
            for (int j = 0; j < 8; ++j)
                t[j] = (__bf16)Blbuf[buf][(quad * 8 + j) * BPAD + nt * 16 + l16];
            bfr[nt] = t;
        }

        asm volatile("s_waitcnt lgkmcnt(0)" ::: "memory");  // my reads done
        asm volatile("s_barrier" ::: "memory");   // everyone's reads done
        if (s + 2 < NKC) issue(s + 2);            // safe to overwrite buf

#pragma unroll
        for (int mt = 0; mt < 4; ++mt)
#pragma unroll
            for (int nt = 0; nt < 4; ++nt)
                acc[mt][nt] = __builtin_amdgcn_mfma_f32_16x16x32_bf16(
                    af[mt], bfr[nt], acc[mt][nt], 0, 0, 0);
    }

    // Epilogue: D[row=quad*4+r][col=l16] per 16x16 tile.
#pragma unroll
    for (int mt = 0; mt < 4; ++mt) {
#pragma unroll
        for (int r = 0; r < 4; ++r) {
            const int c = w * 64 + mt * 16 + quad * 4 + r;
            float* orow = obase + (size_t)c * HWB + l16;
#pragma unroll
            for (int nt = 0; nt < 4; ++nt)
                orow[nt * 16] = acc[mt][nt][r];
        }
    }
}

// ---------------------------------------------------------------------------
extern "C" void kernel_launch(void* const* d_in, const int* in_sizes, int n_in,
                              void* d_out, int out_size, void* d_ws, size_t ws_size,
                              hipStream_t stream) {
    const float* feat = (const float*)d_in[0];   // [4,256,128,256] fp32
    const float* cb   = (const float*)d_in[1];   // [256,256] fp32
    float* out = (float*)d_out;

    __bf16* Mb = (__bf16*)d_ws;                  // 128 KB bf16 M matrix

    prep_kernel<<<NCODES, 256, 0, stream>>>(cb, Mb);

    dim3 grid(HWB / BN, BATCH);                  // 512 x 4 blocks, 256 thr
    recon_kernel<<<grid, 256, 0, stream>>>(feat, Mb, out);
}

// Round 5
// 279.204 us; speedup vs baseline: 1.1223x; 1.0474x over previous
//
#include <hip/hip_runtime.h>
#include <hip/hip_bf16.h>
#include <cstdint>

// Problem constants (fixed by the reference).
#define CDIM   256      // channels == code dim
#define NCODES 256
#define HWB    32768    // H*W = 128*256
#define BATCH  4
#define BM     256      // c-rows per block tile (all of them)
#define BN     256      // pixels per block tile -> 1 KB contiguous per row (DRAM-page friendly)
#define BK     32       // K-chunk
#define NKC    8        // 256 / BK

typedef __bf16 bf16x8 __attribute__((ext_vector_type(8)));
typedef float  f32x4  __attribute__((ext_vector_type(4)));

__device__ __forceinline__ unsigned short bfbits(float f) {
    __bf16 h = (__bf16)f;
    return *(unsigned short*)&h;
}

// ---------------------------------------------------------------------------
// norms: inv_norm[n] = 1 / ||cb[n]||^2. One wave per code row. (r1-verified)
// ---------------------------------------------------------------------------
__global__ void norms_kernel(const float* __restrict__ cb, float* __restrict__ inv_norm) {
    const int n = blockIdx.x;
    const int lane = threadIdx.x;   // 64 threads
    const float* row = cb + n * CDIM;
    float s = 0.f;
#pragma unroll
    for (int c = 0; c < CDIM; c += 64) {
        float v = row[c + lane];
        s += v * v;
    }
#pragma unroll
    for (int off = 32; off > 0; off >>= 1) s += __shfl_down(s, off, 64);
    if (lane == 0) inv_norm[n] = 1.0f / s;
}

// ---------------------------------------------------------------------------
// mmat: M[i][j] = sum_n cb[n][i] * inv_norm[n] * cb[n][j], bf16. (r1-verified)
// ---------------------------------------------------------------------------
__global__ void mmat_kernel(const float* __restrict__ cb, const float* __restrict__ inv_norm,
                            __bf16* __restrict__ Mb) {
    const int i = blockIdx.x;
    const int j = threadIdx.x;
    float acc = 0.f;
#pragma unroll 4
    for (int n = 0; n < NCODES; ++n) {
        acc += (cb[n * CDIM + i] * inv_norm[n]) * cb[n * CDIM + j];
    }
    Mb[i * CDIM + j] = (__bf16)acc;
}

// ---------------------------------------------------------------------------
// recon: out[b,c,p] = sum_k M[c][k] * feat[b,k,p].
// 512-thr (8-wave) blocks, tile 256(c) x 256(p): every HBM read/write touches
// 1 KB contiguous per row per block (DRAM-page friendly — the r1..r4 90-µs
// invariant was 256 B/row page thrashing at ~2.2 TB/s effective).
// LDS (64 KB, double-buffered, XOR-octet swizzled, no padding):
//   A: [r][k] bf16, 256x32; element (r,k) byte = r*64 + ((k>>3)^((r>>1)&3))*16
//                                                + (k&7)*2
//   B: [p][k] bf16 (transposed during staging), same swizzle in p.
// Frag reads are ds_read_b128 at 2-way bank aliasing (free, m136).
// K-loop: one __syncthreads per stage; stage s+1 global loads issued right
// after the barrier, consumed by ds_writes at stage end -> the barrier's
// vmcnt drain has nothing left to wait on.
// Per wave per stage: 4 A-frag + 8 B-frag b128 reads, 32 MFMA (4 mt x 8 nt).
// ---------------------------------------------------------------------------
__global__ __launch_bounds__(512, 2) void recon_kernel(
    const float* __restrict__ feat, const __bf16* __restrict__ Mb,
    float* __restrict__ out) {
    __shared__ __align__(16) unsigned short Abuf[2][BM * BK];  // 2 x 16 KB
    __shared__ __align__(16) unsigned short Bbuf[2][BN * BK];  // 2 x 16 KB

    const int tid  = threadIdx.x;
    const int lane = tid & 63;
    const int w    = tid >> 6;        // wave 0..7
    const int quad = lane >> 4;       // 0..3  (k-octet for frags)
    const int l16  = lane & 15;
    const int wrow = w >> 1;          // c-band: wrow*64
    const int wcol = w & 1;           // p-half: wcol*128

    const int p0 = blockIdx.x * BN;
    const int b  = blockIdx.y;

    const float* fbase = feat + ((size_t)b * CDIM) * HWB + p0;
    float*       obase = out  + ((size_t)b * CDIM) * HWB + p0;

    // Staging identity: sp = row(A)/pixel(B) in [0,256), sg = k-half (0/1).
    const int sp  = tid & 255;
    const int sg  = tid >> 8;
    const int swz = (sp >> 1) & 3;    // XOR-octet swizzle for this row

    // A source: M row sp, k-halves of each 32-k stage. 16B-aligned.
    const unsigned short* asrc = (const unsigned short*)Mb + sp * CDIM + sg * 16;
    // B source: feature column sp of this block's p-window.
    const float* bsrc = fbase + sp;

    uint4 areg[2];
    float breg[16];

    auto load_stage = [&](int s) {
        const unsigned short* a = asrc + s * BK;
        areg[0] = *(const uint4*)(a);
        areg[1] = *(const uint4*)(a + 8);
        const size_t krow0 = (size_t)(s * BK + sg * 16) * HWB;
#pragma unroll
        for (int kk = 0; kk < 16; ++kk)
            breg[kk] = bsrc[krow0 + (size_t)kk * HWB];
    };

    auto write_stage = [&](int buf) {
        char* Ad = (char*)&Abuf[buf][0];
        const int o0 = (sg * 2 + 0) ^ swz;
        const int o1 = (sg * 2 + 1) ^ swz;
        *(uint4*)(Ad + sp * 64 + o0 * 16) = areg[0];
        *(uint4*)(Ad + sp * 64 + o1 * 16) = areg[1];

        char* Bd = (char*)&Bbuf[buf][0];
#pragma unroll
        for (int j = 0; j < 4; ++j) {                 // k-quad within my 16 k's
            const int k  = sg * 16 + j * 4;
            const int oo = (k >> 3) ^ swz;            // swizzled octet
            const int h  = (k >> 2) & 1;              // half within octet
            uint2 v;
            v.x = (unsigned)bfbits(breg[j * 4 + 0]) |
                  ((unsigned)bfbits(breg[j * 4 + 1]) << 16);
            v.y = (unsigned)bfbits(breg[j * 4 + 2]) |
                  ((unsigned)bfbits(breg[j * 4 + 3]) << 16);
            *(uint2*)(Bd + sp * 64 + oo * 16 + h * 8) = v;
        }
    };

    f32x4 acc[4][8];
#pragma unroll
    for (int mt = 0; mt < 4; ++mt)
#pragma unroll
        for (int nt = 0; nt < 8; ++nt)
            acc[mt][nt] = (f32x4){0.f, 0.f, 0.f, 0.f};

    load_stage(0);
    write_stage(0);

    for (int s = 0; s < NKC; ++s) {
        __syncthreads();              // stage-s tiles visible to all waves
        const int buf = s & 1;

        if (s < NKC - 1) load_stage(s + 1);   // fly during MFMA phase

        bf16x8 af[4];
#pragma unroll
        for (int mt = 0; mt < 4; ++mt) {
            const int r = wrow * 64 + mt * 16 + l16;
            af[mt] = *(const bf16x8*)((const char*)&Abuf[buf][0] +
                                      r * 64 + ((quad ^ ((r >> 1) & 3)) * 16));
        }
        bf16x8 bfr[8];
#pragma unroll
        for (int nt = 0; nt < 8; ++nt) {
            const int p = wcol * 128 + nt * 16 + l16;
            bfr[nt] = *(const bf16x8*)((const char*)&Bbuf[buf][0] +
                                       p * 64 + ((quad ^ ((p >> 1) & 3)) * 16));
        }

#pragma unroll
        for (int mt = 0; mt < 4; ++mt)
#pragma unroll
            for (int nt = 0; nt < 8; ++nt)
                acc[mt][nt] = __builtin_amdgcn_mfma_f32_16x16x32_bf16(
                    af[mt], bfr[nt], acc[mt][nt], 0, 0, 0);

        if (s < NKC - 1) write_stage(buf ^ 1);  // vmcnt wait lands here
    }

    // Epilogue: D[row=quad*4+r][col=l16]; block writes 1 KB contiguous per c.
#pragma unroll
    for (int mt = 0; mt < 4; ++mt) {
#pragma unroll
        for (int r = 0; r < 4; ++r) {
            const int c = wrow * 64 + mt * 16 + quad * 4 + r;
            float* orow = obase + (size_t)c * HWB + wcol * 128 + l16;
#pragma unroll
            for (int nt = 0; nt < 8; ++nt)
                orow[nt * 16] = acc[mt][nt][r];
        }
    }
}

// ---------------------------------------------------------------------------
extern "C" void kernel_launch(void* const* d_in, const int* in_sizes, int n_in,
                              void* d_out, int out_size, void* d_ws, size_t ws_size,
                              hipStream_t stream) {
    const float* feat = (const float*)d_in[0];   // [4,256,128,256] fp32
    const float* cb   = (const float*)d_in[1];   // [256,256] fp32
    float* out = (float*)d_out;

    float*  inv_norm = (float*)d_ws;                   // 1 KB
    __bf16* Mb       = (__bf16*)((char*)d_ws + 1024);  // 128 KB bf16 M

    norms_kernel<<<NCODES, 64, 0, stream>>>(cb, inv_norm);
    mmat_kernel<<<NCODES, CDIM, 0, stream>>>(cb, inv_norm, Mb);

    dim3 grid(HWB / BN, BATCH);      // 128 x 4 = 512 blocks, 512 thr
    recon_kernel<<<grid, 512, 0, stream>>>(feat, Mb, out);
}